// Round 2
// baseline (347.551 us; speedup 1.0000x reference)
//
#include <hip/hip_runtime.h>
#include <hip/hip_bf16.h>
#include <math.h>

typedef __attribute__((ext_vector_type(8))) short short8;
typedef __attribute__((ext_vector_type(4))) float f32x4;

__device__ __forceinline__ float b2f(unsigned short u) {
    union { unsigned int i; float f; } v; v.i = ((unsigned int)u) << 16; return v.f;
}
__device__ __forceinline__ unsigned short f2b(float f) {
    __hip_bfloat16 h = __float2bfloat16(f);
    return *reinterpret_cast<unsigned short*>(&h);
}

// ---------------------------------------------------------------------------
// K0: h_grid (128 img, 128 ch, 64x64) fp32  ->  ht (128 img, 4096 pix, 128 ch) bf16
// ---------------------------------------------------------------------------
__global__ __launch_bounds__(256) void transpose_h(const float* __restrict__ hg,
                                                   unsigned short* __restrict__ ht) {
    __shared__ float t[64][65];
    int bid = blockIdx.x;
    int n  = bid >> 7;          // 128 images
    int cb = (bid >> 6) & 1;    // 2 channel blocks of 64
    int pb = bid & 63;          // 64 pixel blocks of 64
    int tid = threadIdx.x;
    int j = tid & 63, i0 = tid >> 6;
    const float* src = hg + ((size_t)(n * 128 + cb * 64)) * 4096 + pb * 64;
#pragma unroll
    for (int ii = 0; ii < 16; ++ii) {
        int i = i0 + ii * 4;
        t[i][j] = src[(size_t)i * 4096 + j];
    }
    __syncthreads();
    int c = tid & 63, j0 = tid >> 6;
    unsigned short* dst = ht + ((size_t)n * 4096 + pb * 64) * 128 + cb * 64 + c;
#pragma unroll
    for (int jj = 0; jj < 16; ++jj) {
        int jr = j0 + jj * 4;
        dst[(size_t)jr * 128] = f2b(t[c][jr]);
    }
}

// ---------------------------------------------------------------------------
// K1: weights -> transposed bf16 ([out_unit][k], contiguous k for MFMA B-frags)
// ---------------------------------------------------------------------------
__global__ void prep_weights(const float* __restrict__ W0, const float* __restrict__ W1,
                             unsigned short* __restrict__ w0t, unsigned short* __restrict__ w1t) {
    int i = blockIdx.x * 256 + threadIdx.x;
    const int total0 = 128 * 384, total1 = 128 * 128;
    for (int idx = i; idx < total0; idx += gridDim.x * 256) {
        int j = idx / 384, k = idx - j * 384;
        w0t[idx] = f2b(W0[k * 128 + j]);
    }
    for (int idx = i; idx < total1; idx += gridDim.x * 256) {
        int j = idx >> 7, k = idx & 127;
        w1t[idx] = f2b(W1[k * 128 + j]);
    }
}

// ---------------------------------------------------------------------------
// K2: fused sample + fourier + MLP — wave-independent, register-resident.
// Each wave owns 16 points. A-fragment layout == gather layout:
//   lane l -> point (l&15), channels/k (l>>4)*8 .. +7 per k-slice.
// No __syncthreads; only per-wave 16x136 bf16 LDS bounce for D->A transpose.
// ---------------------------------------------------------------------------
#define HSTR 136   // shorts per row (272 B, 16B-aligned rows)

__global__ __launch_bounds__(256) void fused_decoder(
    const unsigned short* __restrict__ ht,
    const float* __restrict__ xs, const float* __restrict__ ys,
    const float* __restrict__ Bm,
    const unsigned short* __restrict__ w0t, const float* __restrict__ b0,
    const unsigned short* __restrict__ w1t, const float* __restrict__ b1,
    const float* __restrict__ W2, const float* __restrict__ b2,
    float* __restrict__ out)
{
    __shared__ unsigned short hb_all[4 * 16 * HSTR];

    int tid = threadIdx.x;
    int lane = tid & 63;
    int w = tid >> 6;
    int lr = lane & 15, lg = lane >> 4;
    unsigned short* hb = hb_all + w * 16 * HSTR;

    int n = blockIdx.x >> 5;                       // image
    int pbase = (blockIdx.x & 31) * 64 + w * 16;   // wave's 16 points
    int gp = n * 2048 + pbase + lr;

    // ---- per-lane coords (replicated across the 4 lane-groups, cheap)
    float x = xs[gp], y = ys[gp];
    float px = x * 63.f, py = y * 63.f;            // == (2x-1+1)*0.5*63
    float x0f = fminf(fmaxf(floorf(px), 0.f), 63.f);
    float y0f = fminf(fmaxf(floorf(py), 0.f), 63.f);
    float wx = px - x0f, wy = py - y0f;
    float ivx = 1.f - wx, ivy = 1.f - wy;
    int xi0 = (int)x0f, yi0 = (int)y0f;
    int xi1 = min(xi0 + 1, 63), yi1 = min(yi0 + 1, 63);

    const char* base = (const char*)ht + ((size_t)n << 20) + lg * 16;
    const short8* c00 = (const short8*)(base + (yi0 * 64 + xi0) * 256);
    const short8* c01 = (const short8*)(base + (yi0 * 64 + xi1) * 256);
    const short8* c10 = (const short8*)(base + (yi1 * 64 + xi0) * 256);
    const short8* c11 = (const short8*)(base + (yi1 * 64 + xi1) * 256);

    // ================= layer 0: x(64x384) @ W0(384x128), per wave 16x128 ====
    f32x4 acc[8];
#pragma unroll
    for (int nj = 0; nj < 8; ++nj) {
        float bv = b0[nj * 16 + lr];
        acc[nj] = (f32x4){bv, bv, bv, bv};
    }

    // --- k-slices 0..3: sampled channels, gather+lerp straight into A-frags
#pragma unroll
    for (int ks = 0; ks < 4; ++ks) {
        short8 v00 = c00[ks * 4], v01 = c01[ks * 4];
        short8 v10 = c10[ks * 4], v11 = c11[ks * 4];
        short8 a;
#pragma unroll
        for (int j = 0; j < 8; ++j) {
            float f00 = b2f((unsigned short)v00[j]);
            float f01 = b2f((unsigned short)v01[j]);
            float f10 = b2f((unsigned short)v10[j]);
            float f11 = b2f((unsigned short)v11[j]);
            float top = f00 * ivx + f01 * wx;
            float bot = f10 * ivx + f11 * wx;
            a[j] = (short)f2b(top * ivy + bot * wy);
        }
#pragma unroll
        for (int nj = 0; nj < 8; ++nj) {
            short8 b = *(const short8*)&w0t[(nj * 16 + lr) * 384 + ks * 32 + lg * 8];
            acc[nj] = __builtin_amdgcn_mfma_f32_16x16x32_bf16(a, b, acc[nj], 0, 0, 0);
        }
    }

    // --- k-slices 4..11: fourier (sin: k=128..255, cos: k=256..383)
#pragma unroll
    for (int s = 0; s < 4; ++s) {
        int f0 = s * 32 + lg * 8;
        f32x4 B0a = *(const f32x4*)&Bm[f0];
        f32x4 B0b = *(const f32x4*)&Bm[f0 + 4];
        f32x4 B1a = *(const f32x4*)&Bm[128 + f0];
        f32x4 B1b = *(const f32x4*)&Bm[128 + f0 + 4];
        float t[8];
#pragma unroll
        for (int j = 0; j < 4; ++j) {
            t[j]     = x * B0a[j] + y * B1a[j];
            t[4 + j] = x * B0b[j] + y * B1b[j];
        }
        short8 asn, acs;
#pragma unroll
        for (int j = 0; j < 8; ++j) {
            float tf = t[j] - floorf(t[j]);        // revolutions for HW sin/cos
            float sv, cv;
            asm("v_sin_f32 %0, %1" : "=v"(sv) : "v"(tf));
            asm("v_cos_f32 %0, %1" : "=v"(cv) : "v"(tf));
            asn[j] = (short)f2b(sv);
            acs[j] = (short)f2b(cv);
        }
        int ks_sin = 4 + s, ks_cos = 8 + s;
#pragma unroll
        for (int nj = 0; nj < 8; ++nj) {
            short8 b = *(const short8*)&w0t[(nj * 16 + lr) * 384 + ks_sin * 32 + lg * 8];
            acc[nj] = __builtin_amdgcn_mfma_f32_16x16x32_bf16(asn, b, acc[nj], 0, 0, 0);
        }
#pragma unroll
        for (int nj = 0; nj < 8; ++nj) {
            short8 b = *(const short8*)&w0t[(nj * 16 + lr) * 384 + ks_cos * 32 + lg * 8];
            acc[nj] = __builtin_amdgcn_mfma_f32_16x16x32_bf16(acs, b, acc[nj], 0, 0, 0);
        }
    }

    // relu -> h0 bounce (D layout: row=(lane>>4)*4+r, col=lane&15)
#pragma unroll
    for (int nj = 0; nj < 8; ++nj)
#pragma unroll
        for (int r = 0; r < 4; ++r)
            hb[(lg * 4 + r) * HSTR + nj * 16 + lr] = f2b(fmaxf(acc[nj][r], 0.f));
    asm volatile("s_waitcnt lgkmcnt(0)" ::: "memory");

    // ================= layer 1: h0(64x128) @ W1(128x128) =====================
    short8 a1[4];
#pragma unroll
    for (int ks = 0; ks < 4; ++ks)
        a1[ks] = *(const short8*)&hb[lr * HSTR + ks * 32 + lg * 8];

#pragma unroll
    for (int nj = 0; nj < 8; ++nj) {
        float bv = b1[nj * 16 + lr];
        acc[nj] = (f32x4){bv, bv, bv, bv};
    }
#pragma unroll
    for (int ks = 0; ks < 4; ++ks)
#pragma unroll
        for (int nj = 0; nj < 8; ++nj) {
            short8 b = *(const short8*)&w1t[(nj * 16 + lr) * 128 + ks * 32 + lg * 8];
            acc[nj] = __builtin_amdgcn_mfma_f32_16x16x32_bf16(a1[ks], b, acc[nj], 0, 0, 0);
        }

    asm volatile("s_waitcnt lgkmcnt(0)" ::: "memory");
#pragma unroll
    for (int nj = 0; nj < 8; ++nj)
#pragma unroll
        for (int r = 0; r < 4; ++r)
            hb[(lg * 4 + r) * HSTR + nj * 16 + lr] = f2b(fmaxf(acc[nj][r], 0.f));
    asm volatile("s_waitcnt lgkmcnt(0)" ::: "memory");

    // ================= layer 2: h1(16x128) @ W2(128x2) fp32 ==================
    // lane: point=lr, o=(lg&1), seg=(lg>>1); each sums 64 k's, pair-added via shfl
    int o = lg & 1, seg = lg >> 1;
    float accv = (seg == 0) ? b2[o] : 0.f;
#pragma unroll
    for (int c = 0; c < 8; ++c) {
        short8 hv = *(const short8*)&hb[lr * HSTR + seg * 64 + c * 8];
#pragma unroll
        for (int j = 0; j < 8; ++j)
            accv += b2f((unsigned short)hv[j]) * W2[(seg * 64 + c * 8 + j) * 2 + o];
    }
    accv += __shfl_xor(accv, 32, 64);
    if (seg == 0) {
        int idx = gp * 2 + o;
        if (o == 0) {
            out[idx] = accv;
        } else {
            float sp = (accv > 20.f) ? accv : log1pf(expf(accv));
            out[idx] = sp + 0.01f;
        }
    }
}

// ---------------------------------------------------------------------------
extern "C" void kernel_launch(void* const* d_in, const int* in_sizes, int n_in,
                              void* d_out, int out_size, void* d_ws, size_t ws_size,
                              hipStream_t stream) {
    const float* h_grid = (const float*)d_in[0];
    const float* xs = (const float*)d_in[1];
    const float* ys = (const float*)d_in[2];
    const float* Bm = (const float*)d_in[3];
    const float* W0 = (const float*)d_in[4];
    const float* b0 = (const float*)d_in[5];
    const float* W1 = (const float*)d_in[6];
    const float* b1 = (const float*)d_in[7];
    const float* W2 = (const float*)d_in[8];
    const float* b2 = (const float*)d_in[9];
    float* out = (float*)d_out;

    // workspace carve: ht (134217728 B) | w0t (98304 B) | w1t (32768 B)
    unsigned short* ht  = (unsigned short*)d_ws;
    unsigned short* w0t = (unsigned short*)((char*)d_ws + 134217728ull);
    unsigned short* w1t = w0t + 128 * 384;

    hipLaunchKernelGGL(transpose_h, dim3(16384), dim3(256), 0, stream, h_grid, ht);
    hipLaunchKernelGGL(prep_weights, dim3(64), dim3(256), 0, stream, W0, W1, w0t, w1t);
    hipLaunchKernelGGL(fused_decoder, dim3(4096), dim3(256), 0, stream,
                       ht, xs, ys, Bm, w0t, b0, w1t, b1, W2, b2, out);
}

// Round 3
// 247.002 us; speedup vs baseline: 1.4071x; 1.4071x over previous
//
#include <hip/hip_runtime.h>
#include <hip/hip_bf16.h>
#include <math.h>

typedef __attribute__((ext_vector_type(8))) short short8;
typedef __attribute__((ext_vector_type(4))) float f32x4;

__device__ __forceinline__ float b2f(unsigned short u) {
    union { unsigned int i; float f; } v; v.i = ((unsigned int)u) << 16; return v.f;
}
__device__ __forceinline__ unsigned short f2b(float f) {
    __hip_bfloat16 h = __float2bfloat16(f);
    return *reinterpret_cast<unsigned short*>(&h);
}

// ---------------------------------------------------------------------------
// K0: h_grid (128 img, 128 ch, 64x64) fp32  ->  ht (128 img, 4096 pix, 128 ch) bf16
// ---------------------------------------------------------------------------
__global__ __launch_bounds__(256) void transpose_h(const float* __restrict__ hg,
                                                   unsigned short* __restrict__ ht) {
    __shared__ float t[64][65];
    int bid = blockIdx.x;
    int n  = bid >> 7;
    int cb = (bid >> 6) & 1;
    int pb = bid & 63;
    int tid = threadIdx.x;
    int j = tid & 63, i0 = tid >> 6;
    const float* src = hg + ((size_t)(n * 128 + cb * 64)) * 4096 + pb * 64;
#pragma unroll
    for (int ii = 0; ii < 16; ++ii) {
        int i = i0 + ii * 4;
        t[i][j] = src[(size_t)i * 4096 + j];
    }
    __syncthreads();
    int c = tid & 63, j0 = tid >> 6;
    unsigned short* dst = ht + ((size_t)n * 4096 + pb * 64) * 128 + cb * 64 + c;
#pragma unroll
    for (int jj = 0; jj < 16; ++jj) {
        int jr = j0 + jj * 4;
        dst[(size_t)jr * 128] = f2b(t[c][jr]);
    }
}

// ---------------------------------------------------------------------------
// K1: weights -> transposed bf16 ([out_unit][k], contiguous k for MFMA B-frags)
// ---------------------------------------------------------------------------
__global__ void prep_weights(const float* __restrict__ W0, const float* __restrict__ W1,
                             unsigned short* __restrict__ w0t, unsigned short* __restrict__ w1t) {
    int i = blockIdx.x * 256 + threadIdx.x;
    const int total0 = 128 * 384, total1 = 128 * 128;
    for (int idx = i; idx < total0; idx += gridDim.x * 256) {
        int j = idx / 384, k = idx - j * 384;
        w0t[idx] = f2b(W0[k * 128 + j]);
    }
    for (int idx = i; idx < total1; idx += gridDim.x * 256) {
        int j = idx >> 7, k = idx & 127;
        w1t[idx] = f2b(W1[k * 128 + j]);
    }
}

// ---------------------------------------------------------------------------
// K2: fused. 4 waves/block, 32 points/wave (2 m-tiles), register-resident.
// Pipelined layer0: corner loads for sampled slice s fly under fourier slice s.
// XCD-swizzled blocks for ht L2 locality. Layer2 via MFMA with LDS W2 strip.
// ---------------------------------------------------------------------------
#define HSTR 136

#define MFMA_BF16 __builtin_amdgcn_mfma_f32_16x16x32_bf16

__global__ __launch_bounds__(256) void fused_decoder(
    const unsigned short* __restrict__ ht,
    const float* __restrict__ xs, const float* __restrict__ ys,
    const float* __restrict__ Bm,
    const unsigned short* __restrict__ w0t, const float* __restrict__ b0,
    const unsigned short* __restrict__ w1t, const float* __restrict__ b1,
    const float* __restrict__ W2, const float* __restrict__ b2,
    float* __restrict__ out)
{
    __shared__ unsigned short hb_all[4 * 16 * HSTR];
    __shared__ unsigned short w2l[256];

    int tid = threadIdx.x, lane = tid & 63, w = tid >> 6;
    int lr = lane & 15, lg = lane >> 4;
    unsigned short* hb = hb_all + w * 16 * HSTR;

    // W2 strip into LDS: w2l[o][k], o=0,1
    { int o = tid >> 7, k = tid & 127; w2l[o * 128 + k] = f2b(W2[k * 2 + o]); }
    __syncthreads();

    // bijective XCD swizzle (nwg = 2048 = 8 * 256)
    int bid = blockIdx.x;
    int swz = (bid & 7) * 256 + (bid >> 3);
    int n = swz >> 4;                  // image 0..127
    int pb = (swz & 15) * 128 + w * 32;
    int gp0 = n * 2048 + pb;           // + m*16 + lr -> global point

    // ---- per-m coords
    float xm[2], ym[2], wxv[2], wyv[2];
    int o00[2], o01[2], o10[2], o11[2];
#pragma unroll
    for (int m = 0; m < 2; ++m) {
        int gp = gp0 + m * 16 + lr;
        float x = xs[gp], y = ys[gp];
        xm[m] = x; ym[m] = y;
        float px = x * 63.f, py = y * 63.f;
        float x0f = fminf(fmaxf(floorf(px), 0.f), 63.f);
        float y0f = fminf(fmaxf(floorf(py), 0.f), 63.f);
        wxv[m] = px - x0f; wyv[m] = py - y0f;
        int xi0 = (int)x0f, yi0 = (int)y0f;
        int xi1 = min(xi0 + 1, 63), yi1 = min(yi0 + 1, 63);
        o00[m] = (yi0 * 64 + xi0) * 256;
        o01[m] = (yi0 * 64 + xi1) * 256;
        o10[m] = (yi1 * 64 + xi0) * 256;
        o11[m] = (yi1 * 64 + xi1) * 256;
    }
    const char* base = (const char*)ht + ((size_t)n << 20) + lg * 16;

    // ================= layer 0 =================
    f32x4 acc[2][8];
#pragma unroll
    for (int nj = 0; nj < 8; ++nj) {
        float bv = b0[nj * 16 + lr];
        acc[0][nj] = (f32x4){bv, bv, bv, bv};
        acc[1][nj] = acc[0][nj];
    }

    short8 c00[2], c01[2], c10[2], c11[2];
#pragma unroll
    for (int m = 0; m < 2; ++m) {       // prefetch sampled slice 0
        c00[m] = *(const short8*)(base + o00[m]);
        c01[m] = *(const short8*)(base + o01[m]);
        c10[m] = *(const short8*)(base + o10[m]);
        c11[m] = *(const short8*)(base + o11[m]);
    }

#pragma unroll
    for (int s = 0; s < 4; ++s) {
        // ---- fourier slice s (VALU cover for in-flight corner loads)
        int f0 = s * 32 + lg * 8;
        f32x4 B0a = *(const f32x4*)&Bm[f0];
        f32x4 B0b = *(const f32x4*)&Bm[f0 + 4];
        f32x4 B1a = *(const f32x4*)&Bm[128 + f0];
        f32x4 B1b = *(const f32x4*)&Bm[128 + f0 + 4];
        short8 asn[2], acs[2];
#pragma unroll
        for (int m = 0; m < 2; ++m) {
            float t_[8];
#pragma unroll
            for (int j = 0; j < 4; ++j) {
                t_[j]     = xm[m] * B0a[j] + ym[m] * B1a[j];
                t_[4 + j] = xm[m] * B0b[j] + ym[m] * B1b[j];
            }
#pragma unroll
            for (int j = 0; j < 8; ++j) {
                float tf = t_[j] - floorf(t_[j]);   // revolutions for HW trig
                float sv, cv;
                asm("v_sin_f32 %0, %1" : "=v"(sv) : "v"(tf));
                asm("v_cos_f32 %0, %1" : "=v"(cv) : "v"(tf));
                asn[m][j] = (short)f2b(sv);
                acs[m][j] = (short)f2b(cv);
            }
        }
        int kss = 4 + s, ksc = 8 + s;
#pragma unroll
        for (int nj = 0; nj < 8; ++nj) {
            short8 bs = *(const short8*)&w0t[(nj * 16 + lr) * 384 + kss * 32 + lg * 8];
            acc[0][nj] = MFMA_BF16(asn[0], bs, acc[0][nj], 0, 0, 0);
            acc[1][nj] = MFMA_BF16(asn[1], bs, acc[1][nj], 0, 0, 0);
        }
#pragma unroll
        for (int nj = 0; nj < 8; ++nj) {
            short8 bc = *(const short8*)&w0t[(nj * 16 + lr) * 384 + ksc * 32 + lg * 8];
            acc[0][nj] = MFMA_BF16(acs[0], bc, acc[0][nj], 0, 0, 0);
            acc[1][nj] = MFMA_BF16(acs[1], bc, acc[1][nj], 0, 0, 0);
        }

        // ---- sampled slice s: lerp (waits loads), reissue next, MFMA
        short8 a[2];
#pragma unroll
        for (int m = 0; m < 2; ++m) {
            float wx = wxv[m], wy = wyv[m];
            float ivx = 1.f - wx, ivy = 1.f - wy;
#pragma unroll
            for (int j = 0; j < 8; ++j) {
                float top = b2f((unsigned short)c00[m][j]) * ivx + b2f((unsigned short)c01[m][j]) * wx;
                float bot = b2f((unsigned short)c10[m][j]) * ivx + b2f((unsigned short)c11[m][j]) * wx;
                a[m][j] = (short)f2b(top * ivy + bot * wy);
            }
        }
        if (s < 3) {
            int so = (s + 1) * 64;
#pragma unroll
            for (int m = 0; m < 2; ++m) {
                c00[m] = *(const short8*)(base + o00[m] + so);
                c01[m] = *(const short8*)(base + o01[m] + so);
                c10[m] = *(const short8*)(base + o10[m] + so);
                c11[m] = *(const short8*)(base + o11[m] + so);
            }
        }
#pragma unroll
        for (int nj = 0; nj < 8; ++nj) {
            short8 b = *(const short8*)&w0t[(nj * 16 + lr) * 384 + s * 32 + lg * 8];
            acc[0][nj] = MFMA_BF16(a[0], b, acc[0][nj], 0, 0, 0);
            acc[1][nj] = MFMA_BF16(a[1], b, acc[1][nj], 0, 0, 0);
        }
    }

    // ================= layer 1: h0(32x128) @ W1(128x128) =================
    short8 a1[2][4];
#pragma unroll
    for (int m = 0; m < 2; ++m) {
#pragma unroll
        for (int nj = 0; nj < 8; ++nj)
#pragma unroll
            for (int r = 0; r < 4; ++r)
                hb[(lg * 4 + r) * HSTR + nj * 16 + lr] = f2b(fmaxf(acc[m][nj][r], 0.f));
        asm volatile("s_waitcnt lgkmcnt(0)" ::: "memory");
#pragma unroll
        for (int ks = 0; ks < 4; ++ks)
            a1[m][ks] = *(const short8*)&hb[lr * HSTR + ks * 32 + lg * 8];
        asm volatile("s_waitcnt lgkmcnt(0)" ::: "memory");
    }
#pragma unroll
    for (int nj = 0; nj < 8; ++nj) {
        float bv = b1[nj * 16 + lr];
        acc[0][nj] = (f32x4){bv, bv, bv, bv};
        acc[1][nj] = acc[0][nj];
    }
#pragma unroll
    for (int ks = 0; ks < 4; ++ks)
#pragma unroll
        for (int nj = 0; nj < 8; ++nj) {
            short8 b = *(const short8*)&w1t[(nj * 16 + lr) * 128 + ks * 32 + lg * 8];
            acc[0][nj] = MFMA_BF16(a1[0][ks], b, acc[0][nj], 0, 0, 0);
            acc[1][nj] = MFMA_BF16(a1[1][ks], b, acc[1][nj], 0, 0, 0);
        }

    // ================= layer 2: h1 @ W2 via MFMA (zero-padded B) =============
    float bb2 = (lr < 2) ? b2[lr] : 0.f;
#pragma unroll
    for (int m = 0; m < 2; ++m) {
#pragma unroll
        for (int nj = 0; nj < 8; ++nj)
#pragma unroll
            for (int r = 0; r < 4; ++r)
                hb[(lg * 4 + r) * HSTR + nj * 16 + lr] = f2b(fmaxf(acc[m][nj][r], 0.f));
        asm volatile("s_waitcnt lgkmcnt(0)" ::: "memory");
        f32x4 acc2 = (f32x4){bb2, bb2, bb2, bb2};
#pragma unroll
        for (int ks = 0; ks < 4; ++ks) {
            short8 a2 = *(const short8*)&hb[lr * HSTR + ks * 32 + lg * 8];
            short8 bz = (short8){0, 0, 0, 0, 0, 0, 0, 0};
            if (lr < 2) bz = *(const short8*)&w2l[lr * 128 + ks * 32 + lg * 8];
            acc2 = MFMA_BF16(a2, bz, acc2, 0, 0, 0);
        }
        asm volatile("s_waitcnt lgkmcnt(0)" ::: "memory");
        if (lr < 2) {
#pragma unroll
            for (int r = 0; r < 4; ++r) {
                int gp = gp0 + m * 16 + lg * 4 + r;
                float v = acc2[r];
                if (lr == 0) {
                    out[gp * 2] = v;
                } else {
                    float sp = (v > 20.f) ? v : log1pf(expf(v));
                    out[gp * 2 + 1] = sp + 0.01f;
                }
            }
        }
    }
}

// ---------------------------------------------------------------------------
extern "C" void kernel_launch(void* const* d_in, const int* in_sizes, int n_in,
                              void* d_out, int out_size, void* d_ws, size_t ws_size,
                              hipStream_t stream) {
    const float* h_grid = (const float*)d_in[0];
    const float* xs = (const float*)d_in[1];
    const float* ys = (const float*)d_in[2];
    const float* Bm = (const float*)d_in[3];
    const float* W0 = (const float*)d_in[4];
    const float* b0 = (const float*)d_in[5];
    const float* W1 = (const float*)d_in[6];
    const float* b1 = (const float*)d_in[7];
    const float* W2 = (const float*)d_in[8];
    const float* b2 = (const float*)d_in[9];
    float* out = (float*)d_out;

    // workspace carve: ht (134217728 B) | w0t (98304 B) | w1t (32768 B)
    unsigned short* ht  = (unsigned short*)d_ws;
    unsigned short* w0t = (unsigned short*)((char*)d_ws + 134217728ull);
    unsigned short* w1t = w0t + 128 * 384;

    hipLaunchKernelGGL(transpose_h, dim3(16384), dim3(256), 0, stream, h_grid, ht);
    hipLaunchKernelGGL(prep_weights, dim3(64), dim3(256), 0, stream, W0, W1, w0t, w1t);
    hipLaunchKernelGGL(fused_decoder, dim3(2048), dim3(256), 0, stream,
                       ht, xs, ys, Bm, w0t, b0, w1t, b1, W2, b2, out);
}

// Round 4
// 210.690 us; speedup vs baseline: 1.6496x; 1.1724x over previous
//
#include <hip/hip_runtime.h>
#include <hip/hip_bf16.h>
#include <math.h>

typedef __attribute__((ext_vector_type(8))) short short8;
typedef __attribute__((ext_vector_type(4))) float f32x4;

__device__ __forceinline__ float b2f(unsigned short u) {
    union { unsigned int i; float f; } v; v.i = ((unsigned int)u) << 16; return v.f;
}
__device__ __forceinline__ unsigned short f2b(float f) {
    __hip_bfloat16 h = __float2bfloat16(f);
    return *reinterpret_cast<unsigned short*>(&h);
}

// ---------------------------------------------------------------------------
// K0: h_grid (128 img, 128 ch, 64x64) fp32  ->  ht (128 img, 4096 pix, 128 ch) bf16
// ---------------------------------------------------------------------------
__global__ __launch_bounds__(256) void transpose_h(const float* __restrict__ hg,
                                                   unsigned short* __restrict__ ht) {
    __shared__ float t[64][65];
    int bid = blockIdx.x;
    int n  = bid >> 7;
    int cb = (bid >> 6) & 1;
    int pb = bid & 63;
    int tid = threadIdx.x;
    int j = tid & 63, i0 = tid >> 6;
    const float* src = hg + ((size_t)(n * 128 + cb * 64)) * 4096 + pb * 64;
#pragma unroll
    for (int ii = 0; ii < 16; ++ii) {
        int i = i0 + ii * 4;
        t[i][j] = src[(size_t)i * 4096 + j];
    }
    __syncthreads();
    int c = tid & 63, j0 = tid >> 6;
    unsigned short* dst = ht + ((size_t)n * 4096 + pb * 64) * 128 + cb * 64 + c;
#pragma unroll
    for (int jj = 0; jj < 16; ++jj) {
        int jr = j0 + jj * 4;
        dst[(size_t)jr * 128] = f2b(t[c][jr]);
    }
}

// ---------------------------------------------------------------------------
// K1: weights -> transposed bf16 ([out_unit][k] contiguous k)
// ---------------------------------------------------------------------------
__global__ void prep_weights(const float* __restrict__ W0, const float* __restrict__ W1,
                             unsigned short* __restrict__ w0t, unsigned short* __restrict__ w1t) {
    int i = blockIdx.x * 256 + threadIdx.x;
    const int total0 = 128 * 384, total1 = 128 * 128;
    for (int idx = i; idx < total0; idx += gridDim.x * 256) {
        int j = idx / 384, k = idx - j * 384;
        w0t[idx] = f2b(W0[k * 128 + j]);
    }
    for (int idx = i; idx < total1; idx += gridDim.x * 256) {
        int j = idx >> 7, k = idx & 127;
        w1t[idx] = f2b(W1[k * 128 + j]);
    }
}

// ---------------------------------------------------------------------------
// K2: fused. 512 threads (8 waves), 32 points/wave, 256 points/block.
// W0 staged in LDS (XOR-swizzled) once per block; W1 from global (L1-hot).
// 1 block/CU (133 KB LDS), 2 waves/SIMD.
// ---------------------------------------------------------------------------
#define HSTR 136
#define MFMA_BF16 __builtin_amdgcn_mfma_f32_16x16x32_bf16

__device__ __forceinline__ const short8* w0frag(const unsigned short* w0s, int row, int kb) {
    // row: output unit 0..127 (768 B rows); kb: byte offset in row (16B-aligned)
    return (const short8*)((const char*)w0s + row * 768 + (kb ^ ((row & 7) << 4)));
}

__global__ __launch_bounds__(512, 2) void fused_decoder(
    const unsigned short* __restrict__ ht,
    const float* __restrict__ xs, const float* __restrict__ ys,
    const float* __restrict__ Bm,
    const unsigned short* __restrict__ w0t, const float* __restrict__ b0,
    const unsigned short* __restrict__ w1t, const float* __restrict__ b1,
    const float* __restrict__ W2, const float* __restrict__ b2,
    float* __restrict__ out)
{
    __shared__ unsigned short w0s[128 * 384];      // 96 KB, swizzled rows
    __shared__ unsigned short hb_all[8 * 16 * HSTR]; // 34 KB bounce
    __shared__ unsigned short w2l[256];            // 0.5 KB

    int tid = threadIdx.x, lane = tid & 63, w = tid >> 6;
    int lr = lane & 15, lg = lane >> 4;
    unsigned short* hb = hb_all + w * 16 * HSTR;

    // ---- stage W0 into LDS with XOR swizzle (6144 16B-chunks, 12/thread)
    {
        const short8* src = (const short8*)w0t;
#pragma unroll
        for (int it = 0; it < 12; ++it) {
            int c = tid + it * 512;
            int row = c / 48;                     // 48 chunks per 768B row
            int wb = (c - row * 48) * 16;
            short8 v = src[c];
            *(short8*)((char*)w0s + row * 768 + (wb ^ ((row & 7) << 4))) = v;
        }
        if (tid < 256) { int o = tid >> 7, k = tid & 127; w2l[o * 128 + k] = f2b(W2[k * 2 + o]); }
    }
    __syncthreads();

    // bijective XCD swizzle (nwg = 1024 = 8 * 128)
    int bid = blockIdx.x;
    int swz = (bid & 7) * 128 + (bid >> 3);
    int n = swz >> 3;                    // image 0..127
    int pbw = (swz & 7) * 256 + w * 32;  // wave's 32 points within image
    int gp0 = n * 2048 + pbw;

    // ---- per-m coords
    float xm[2], ym[2], wxv[2], wyv[2];
    int o00[2], o01[2], o10[2], o11[2];
#pragma unroll
    for (int m = 0; m < 2; ++m) {
        int gp = gp0 + m * 16 + lr;
        float x = xs[gp], y = ys[gp];
        xm[m] = x; ym[m] = y;
        float px = x * 63.f, py = y * 63.f;
        float x0f = fminf(fmaxf(floorf(px), 0.f), 63.f);
        float y0f = fminf(fmaxf(floorf(py), 0.f), 63.f);
        wxv[m] = px - x0f; wyv[m] = py - y0f;
        int xi0 = (int)x0f, yi0 = (int)y0f;
        int xi1 = min(xi0 + 1, 63), yi1 = min(yi0 + 1, 63);
        o00[m] = (yi0 * 64 + xi0) * 256;
        o01[m] = (yi0 * 64 + xi1) * 256;
        o10[m] = (yi1 * 64 + xi0) * 256;
        o11[m] = (yi1 * 64 + xi1) * 256;
    }
    const char* base = (const char*)ht + ((size_t)n << 20) + lg * 16;

    // ================= layer 0 =================
    f32x4 acc[2][8];
#pragma unroll
    for (int nj = 0; nj < 8; ++nj) {
        float bv = b0[nj * 16 + lr];
        acc[0][nj] = (f32x4){bv, bv, bv, bv};
        acc[1][nj] = acc[0][nj];
    }

    short8 c00[2], c01[2], c10[2], c11[2];
#pragma unroll
    for (int m = 0; m < 2; ++m) {        // prefetch sampled slice 0
        c00[m] = *(const short8*)(base + o00[m]);
        c01[m] = *(const short8*)(base + o01[m]);
        c10[m] = *(const short8*)(base + o10[m]);
        c11[m] = *(const short8*)(base + o11[m]);
    }

#pragma unroll
    for (int s = 0; s < 4; ++s) {
        // ---- fourier slice s (VALU cover for in-flight corner loads)
        int f0 = s * 32 + lg * 8;
        f32x4 B0a = *(const f32x4*)&Bm[f0];
        f32x4 B0b = *(const f32x4*)&Bm[f0 + 4];
        f32x4 B1a = *(const f32x4*)&Bm[128 + f0];
        f32x4 B1b = *(const f32x4*)&Bm[128 + f0 + 4];
        short8 asn[2], acs[2];
#pragma unroll
        for (int m = 0; m < 2; ++m) {
            float t_[8];
#pragma unroll
            for (int j = 0; j < 4; ++j) {
                t_[j]     = xm[m] * B0a[j] + ym[m] * B1a[j];
                t_[4 + j] = xm[m] * B0b[j] + ym[m] * B1b[j];
            }
#pragma unroll
            for (int j = 0; j < 8; ++j) {
                float tf = t_[j] - floorf(t_[j]);   // revolutions for HW trig
                float sv, cv;
                asm("v_sin_f32 %0, %1" : "=v"(sv) : "v"(tf));
                asm("v_cos_f32 %0, %1" : "=v"(cv) : "v"(tf));
                asn[m][j] = (short)f2b(sv);
                acs[m][j] = (short)f2b(cv);
            }
        }
        int kbs = (4 + s) * 64 + lg * 16, kbc = (8 + s) * 64 + lg * 16;
#pragma unroll
        for (int nj = 0; nj < 8; ++nj) {
            short8 bs = *w0frag(w0s, nj * 16 + lr, kbs);
            acc[0][nj] = MFMA_BF16(asn[0], bs, acc[0][nj], 0, 0, 0);
            acc[1][nj] = MFMA_BF16(asn[1], bs, acc[1][nj], 0, 0, 0);
        }
#pragma unroll
        for (int nj = 0; nj < 8; ++nj) {
            short8 bc = *w0frag(w0s, nj * 16 + lr, kbc);
            acc[0][nj] = MFMA_BF16(acs[0], bc, acc[0][nj], 0, 0, 0);
            acc[1][nj] = MFMA_BF16(acs[1], bc, acc[1][nj], 0, 0, 0);
        }

        // ---- sampled slice s: lerp (waits loads), reissue next, MFMA
        short8 a[2];
#pragma unroll
        for (int m = 0; m < 2; ++m) {
            float wx = wxv[m], wy = wyv[m];
            float ivx = 1.f - wx, ivy = 1.f - wy;
#pragma unroll
            for (int j = 0; j < 8; ++j) {
                float top = b2f((unsigned short)c00[m][j]) * ivx + b2f((unsigned short)c01[m][j]) * wx;
                float bot = b2f((unsigned short)c10[m][j]) * ivx + b2f((unsigned short)c11[m][j]) * wx;
                a[m][j] = (short)f2b(top * ivy + bot * wy);
            }
        }
        if (s < 3) {
            int so = (s + 1) * 64;
#pragma unroll
            for (int m = 0; m < 2; ++m) {
                c00[m] = *(const short8*)(base + o00[m] + so);
                c01[m] = *(const short8*)(base + o01[m] + so);
                c10[m] = *(const short8*)(base + o10[m] + so);
                c11[m] = *(const short8*)(base + o11[m] + so);
            }
        }
        int kba = s * 64 + lg * 16;
#pragma unroll
        for (int nj = 0; nj < 8; ++nj) {
            short8 b = *w0frag(w0s, nj * 16 + lr, kba);
            acc[0][nj] = MFMA_BF16(a[0], b, acc[0][nj], 0, 0, 0);
            acc[1][nj] = MFMA_BF16(a[1], b, acc[1][nj], 0, 0, 0);
        }
    }

    // ================= layer 1: h0(32x128) @ W1(128x128) =================
    short8 a1[2][4];
#pragma unroll
    for (int m = 0; m < 2; ++m) {
#pragma unroll
        for (int nj = 0; nj < 8; ++nj)
#pragma unroll
            for (int r = 0; r < 4; ++r)
                hb[(lg * 4 + r) * HSTR + nj * 16 + lr] = f2b(fmaxf(acc[m][nj][r], 0.f));
        asm volatile("s_waitcnt lgkmcnt(0)" ::: "memory");
#pragma unroll
        for (int ks = 0; ks < 4; ++ks)
            a1[m][ks] = *(const short8*)&hb[lr * HSTR + ks * 32 + lg * 8];
        asm volatile("s_waitcnt lgkmcnt(0)" ::: "memory");
    }
#pragma unroll
    for (int nj = 0; nj < 8; ++nj) {
        float bv = b1[nj * 16 + lr];
        acc[0][nj] = (f32x4){bv, bv, bv, bv};
        acc[1][nj] = acc[0][nj];
    }
#pragma unroll
    for (int ks = 0; ks < 4; ++ks)
#pragma unroll
        for (int nj = 0; nj < 8; ++nj) {
            short8 b = *(const short8*)&w1t[(nj * 16 + lr) * 128 + ks * 32 + lg * 8];
            acc[0][nj] = MFMA_BF16(a1[0][ks], b, acc[0][nj], 0, 0, 0);
            acc[1][nj] = MFMA_BF16(a1[1][ks], b, acc[1][nj], 0, 0, 0);
        }

    // ================= layer 2: h1 @ W2 via MFMA (zero-padded B) =============
    float bb2 = (lr < 2) ? b2[lr] : 0.f;
#pragma unroll
    for (int m = 0; m < 2; ++m) {
#pragma unroll
        for (int nj = 0; nj < 8; ++nj)
#pragma unroll
            for (int r = 0; r < 4; ++r)
                hb[(lg * 4 + r) * HSTR + nj * 16 + lr] = f2b(fmaxf(acc[m][nj][r], 0.f));
        asm volatile("s_waitcnt lgkmcnt(0)" ::: "memory");
        f32x4 acc2 = (f32x4){bb2, bb2, bb2, bb2};
#pragma unroll
        for (int ks = 0; ks < 4; ++ks) {
            short8 a2 = *(const short8*)&hb[lr * HSTR + ks * 32 + lg * 8];
            short8 bz = (short8){0, 0, 0, 0, 0, 0, 0, 0};
            if (lr < 2) bz = *(const short8*)&w2l[lr * 128 + ks * 32 + lg * 8];
            acc2 = MFMA_BF16(a2, bz, acc2, 0, 0, 0);
        }
        asm volatile("s_waitcnt lgkmcnt(0)" ::: "memory");
        if (lr < 2) {
#pragma unroll
            for (int r = 0; r < 4; ++r) {
                int gp = gp0 + m * 16 + lg * 4 + r;
                float v = acc2[r];
                if (lr == 0) {
                    out[gp * 2] = v;
                } else {
                    float sp = (v > 20.f) ? v : log1pf(expf(v));
                    out[gp * 2 + 1] = sp + 0.01f;
                }
            }
        }
    }
}

// ---------------------------------------------------------------------------
extern "C" void kernel_launch(void* const* d_in, const int* in_sizes, int n_in,
                              void* d_out, int out_size, void* d_ws, size_t ws_size,
                              hipStream_t stream) {
    const float* h_grid = (const float*)d_in[0];
    const float* xs = (const float*)d_in[1];
    const float* ys = (const float*)d_in[2];
    const float* Bm = (const float*)d_in[3];
    const float* W0 = (const float*)d_in[4];
    const float* b0 = (const float*)d_in[5];
    const float* W1 = (const float*)d_in[6];
    const float* b1 = (const float*)d_in[7];
    const float* W2 = (const float*)d_in[8];
    const float* b2 = (const float*)d_in[9];
    float* out = (float*)d_out;

    // workspace carve: ht (134217728 B) | w0t (98304 B) | w1t (32768 B)
    unsigned short* ht  = (unsigned short*)d_ws;
    unsigned short* w0t = (unsigned short*)((char*)d_ws + 134217728ull);
    unsigned short* w1t = w0t + 128 * 384;

    hipLaunchKernelGGL(transpose_h, dim3(16384), dim3(256), 0, stream, h_grid, ht);
    hipLaunchKernelGGL(prep_weights, dim3(64), dim3(256), 0, stream, W0, W1, w0t, w1t);
    hipLaunchKernelGGL(fused_decoder, dim3(1024), dim3(512), 0, stream,
                       ht, xs, ys, Bm, w0t, b0, w1t, b1, W2, b2, out);
}

// Round 5
// 208.566 us; speedup vs baseline: 1.6664x; 1.0102x over previous
//
#include <hip/hip_runtime.h>
#include <hip/hip_bf16.h>
#include <math.h>

typedef __attribute__((ext_vector_type(8))) short short8;
typedef __attribute__((ext_vector_type(4))) float f32x4;

__device__ __forceinline__ float b2f(unsigned short u) {
    union { unsigned int i; float f; } v; v.i = ((unsigned int)u) << 16; return v.f;
}
__device__ __forceinline__ unsigned short f2b(float f) {
    __hip_bfloat16 h = __float2bfloat16(f);
    return *reinterpret_cast<unsigned short*>(&h);
}

// ---------------------------------------------------------------------------
// K0: h_grid (128 img, 128 ch, 64x64) fp32  ->  ht (128 img, 4096 pix, 128 ch) bf16
// ---------------------------------------------------------------------------
__global__ __launch_bounds__(256) void transpose_h(const float* __restrict__ hg,
                                                   unsigned short* __restrict__ ht) {
    __shared__ float t[64][65];
    int bid = blockIdx.x;
    int n  = bid >> 7;
    int cb = (bid >> 6) & 1;
    int pb = bid & 63;
    int tid = threadIdx.x;
    int j = tid & 63, i0 = tid >> 6;
    const float* src = hg + ((size_t)(n * 128 + cb * 64)) * 4096 + pb * 64;
#pragma unroll
    for (int ii = 0; ii < 16; ++ii) {
        int i = i0 + ii * 4;
        t[i][j] = src[(size_t)i * 4096 + j];
    }
    __syncthreads();
    int c = tid & 63, j0 = tid >> 6;
    unsigned short* dst = ht + ((size_t)n * 4096 + pb * 64) * 128 + cb * 64 + c;
#pragma unroll
    for (int jj = 0; jj < 16; ++jj) {
        int jr = j0 + jj * 4;
        dst[(size_t)jr * 128] = f2b(t[c][jr]);
    }
}

// ---------------------------------------------------------------------------
// K1: weights -> transposed bf16 ([out_unit][k] contiguous k) + padded W2 strip
// ---------------------------------------------------------------------------
__global__ void prep_weights(const float* __restrict__ W0, const float* __restrict__ W1,
                             const float* __restrict__ W2,
                             unsigned short* __restrict__ w0t, unsigned short* __restrict__ w1t,
                             unsigned short* __restrict__ w2p) {
    int i = blockIdx.x * 256 + threadIdx.x;
    const int total0 = 128 * 384, total1 = 128 * 128, total2 = 16 * 128;
    for (int idx = i; idx < total0; idx += gridDim.x * 256) {
        int j = idx / 384, k = idx - j * 384;
        w0t[idx] = f2b(W0[k * 128 + j]);
    }
    for (int idx = i; idx < total1; idx += gridDim.x * 256) {
        int j = idx >> 7, k = idx & 127;
        w1t[idx] = f2b(W1[k * 128 + j]);
    }
    for (int idx = i; idx < total2; idx += gridDim.x * 256) {
        int r = idx >> 7, k = idx & 127;
        w2p[idx] = (r < 2) ? f2b(W2[k * 2 + r]) : (unsigned short)0;
    }
}

// ---------------------------------------------------------------------------
// K2: fused. 1024 threads = 16 waves, 16 points/wave, 256 points/block.
// W0 in LDS (XOR-swizzled, 96 KB) + per-wave 16x128 bounce (64 KB) = 160 KB.
// 1 block/CU but 16 waves -> 4 waves/SIMD. TLP-first design.
// ---------------------------------------------------------------------------
#define MFMA_BF16 __builtin_amdgcn_mfma_f32_16x16x32_bf16

__global__ __launch_bounds__(1024, 4) void fused_decoder(
    const unsigned short* __restrict__ ht,
    const float* __restrict__ xs, const float* __restrict__ ys,
    const float* __restrict__ Bm,
    const unsigned short* __restrict__ w0t, const float* __restrict__ b0,
    const unsigned short* __restrict__ w1t, const float* __restrict__ b1,
    const unsigned short* __restrict__ w2p, const float* __restrict__ b2,
    float* __restrict__ out)
{
    __shared__ unsigned short smem[81920];           // 160 KB exactly
    unsigned short* w0s = smem;                      // 49152 shorts (96 KB)
    int tid = threadIdx.x, lane = tid & 63, w = tid >> 6;
    int lr = lane & 15, lg = lane >> 4;
    char* hb = (char*)(smem + 49152 + w * 2048);     // per-wave 16x128 bf16 (4 KB)

    // ---- stage W0 into LDS with XOR swizzle (6144 16B-chunks, 6/thread)
    {
        const short8* src = (const short8*)w0t;
#pragma unroll
        for (int it = 0; it < 6; ++it) {
            int c = tid + it * 1024;
            int row = c / 48;                        // 48 chunks per 768 B row
            int wb = (c - row * 48) * 16;
            short8 v = src[c];
            *(short8*)((char*)w0s + row * 768 + (wb ^ ((row & 7) << 4))) = v;
        }
    }
    __syncthreads();

    // block -> (xcd, slot) -> image/tile so concurrent blocks per XCD share ~4 images
    int bid = blockIdx.x;
    int x = bid & 7, s = bid >> 3;                   // 1024 = 8 * 128
    int n = x * 16 + (s >> 3);                       // image 0..127
    int pt = s & 7;                                  // tile 0..7 within image
    int gp0 = n * 2048 + pt * 256 + w * 16;
    int gp = gp0 + lr;

    // ---- per-lane coords (replicated over lg groups)
    float xc = xs[gp], yc = ys[gp];
    float px = xc * 63.f, py = yc * 63.f;
    float x0f = fminf(fmaxf(floorf(px), 0.f), 63.f);
    float y0f = fminf(fmaxf(floorf(py), 0.f), 63.f);
    float wx = px - x0f, wy = py - y0f;
    float ivx = 1.f - wx, ivy = 1.f - wy;
    int xi0 = (int)x0f, yi0 = (int)y0f;
    int xi1 = min(xi0 + 1, 63), yi1 = min(yi0 + 1, 63);
    const char* base = (const char*)ht + ((size_t)n << 20) + lg * 16;
    int o00 = (yi0 * 64 + xi0) * 256, o01 = (yi0 * 64 + xi1) * 256;
    int o10 = (yi1 * 64 + xi0) * 256, o11 = (yi1 * 64 + xi1) * 256;

    // ================= layer 0: x(16x384) @ W0(384x128) =================
    f32x4 acc[8];
#pragma unroll
    for (int nj = 0; nj < 8; ++nj) {
        float bv = b0[nj * 16 + lr];
        acc[nj] = (f32x4){bv, bv, bv, bv};
    }

#pragma unroll
    for (int s4 = 0; s4 < 4; ++s4) {
        // issue corner loads first (latency covered by fourier VALU below)
        short8 c00 = *(const short8*)(base + o00 + s4 * 64);
        short8 c01 = *(const short8*)(base + o01 + s4 * 64);
        short8 c10 = *(const short8*)(base + o10 + s4 * 64);
        short8 c11 = *(const short8*)(base + o11 + s4 * 64);

        // ---- fourier slice s4
        int f0 = s4 * 32 + lg * 8;
        f32x4 B0a = *(const f32x4*)&Bm[f0];
        f32x4 B0b = *(const f32x4*)&Bm[f0 + 4];
        f32x4 B1a = *(const f32x4*)&Bm[128 + f0];
        f32x4 B1b = *(const f32x4*)&Bm[128 + f0 + 4];
        float t_[8];
#pragma unroll
        for (int j = 0; j < 4; ++j) {
            t_[j]     = xc * B0a[j] + yc * B1a[j];
            t_[4 + j] = xc * B0b[j] + yc * B1b[j];
        }
        short8 asn, acs;
#pragma unroll
        for (int j = 0; j < 8; ++j) {
            float tf = t_[j] - floorf(t_[j]);        // revolutions for HW trig
            float sv, cv;
            asm("v_sin_f32 %0, %1" : "=v"(sv) : "v"(tf));
            asm("v_cos_f32 %0, %1" : "=v"(cv) : "v"(tf));
            asn[j] = (short)f2b(sv);
            acs[j] = (short)f2b(cv);
        }
        int kbs = (4 + s4) * 64 + lg * 16, kbc = (8 + s4) * 64 + lg * 16;
#pragma unroll
        for (int nj = 0; nj < 8; ++nj) {
            int row = nj * 16 + lr;
            short8 bs = *(const short8*)((const char*)w0s + row * 768 + (kbs ^ ((lr & 7) << 4)));
            acc[nj] = MFMA_BF16(asn, bs, acc[nj], 0, 0, 0);
        }
#pragma unroll
        for (int nj = 0; nj < 8; ++nj) {
            int row = nj * 16 + lr;
            short8 bc = *(const short8*)((const char*)w0s + row * 768 + (kbc ^ ((lr & 7) << 4)));
            acc[nj] = MFMA_BF16(acs, bc, acc[nj], 0, 0, 0);
        }

        // ---- sampled slice s4 (lerp waits for corner loads)
        short8 a;
#pragma unroll
        for (int j = 0; j < 8; ++j) {
            float top = b2f((unsigned short)c00[j]) * ivx + b2f((unsigned short)c01[j]) * wx;
            float bot = b2f((unsigned short)c10[j]) * ivx + b2f((unsigned short)c11[j]) * wx;
            a[j] = (short)f2b(top * ivy + bot * wy);
        }
        int kba = s4 * 64 + lg * 16;
#pragma unroll
        for (int nj = 0; nj < 8; ++nj) {
            int row = nj * 16 + lr;
            short8 b = *(const short8*)((const char*)w0s + row * 768 + (kba ^ ((lr & 7) << 4)));
            acc[nj] = MFMA_BF16(a, b, acc[nj], 0, 0, 0);
        }
    }

    // ================= layer 1: h0(16x128) @ W1(128x128) =================
    // bounce D->A through per-wave swizzled LDS (2-way conflicts max)
#pragma unroll
    for (int nj = 0; nj < 8; ++nj)
#pragma unroll
        for (int r = 0; r < 4; ++r) {
            int row = lg * 4 + r;
            int cb2 = (nj * 16 + lr) * 2;
            *(unsigned short*)(hb + row * 256 + (cb2 ^ ((row & 7) << 4))) =
                f2b(fmaxf(acc[nj][r], 0.f));
        }
    asm volatile("s_waitcnt lgkmcnt(0)" ::: "memory");
    short8 a1[4];
#pragma unroll
    for (int ks = 0; ks < 4; ++ks)
        a1[ks] = *(const short8*)(hb + lr * 256 + ((ks * 64 + lg * 16) ^ ((lr & 7) << 4)));
    asm volatile("s_waitcnt lgkmcnt(0)" ::: "memory");

#pragma unroll
    for (int nj = 0; nj < 8; ++nj) {
        float bv = b1[nj * 16 + lr];
        acc[nj] = (f32x4){bv, bv, bv, bv};
    }
#pragma unroll
    for (int ks = 0; ks < 4; ++ks)
#pragma unroll
        for (int nj = 0; nj < 8; ++nj) {
            short8 b = *(const short8*)&w1t[(nj * 16 + lr) * 128 + ks * 32 + lg * 8];
            acc[nj] = MFMA_BF16(a1[ks], b, acc[nj], 0, 0, 0);
        }

    // ================= layer 2: h1(16x128) @ W2p(128x16, cols>=2 zero) ======
#pragma unroll
    for (int nj = 0; nj < 8; ++nj)
#pragma unroll
        for (int r = 0; r < 4; ++r) {
            int row = lg * 4 + r;
            int cb2 = (nj * 16 + lr) * 2;
            *(unsigned short*)(hb + row * 256 + (cb2 ^ ((row & 7) << 4))) =
                f2b(fmaxf(acc[nj][r], 0.f));
        }
    asm volatile("s_waitcnt lgkmcnt(0)" ::: "memory");
    float bb2 = (lr < 2) ? b2[lr] : 0.f;
    f32x4 acc2 = (f32x4){bb2, bb2, bb2, bb2};
#pragma unroll
    for (int ks = 0; ks < 4; ++ks) {
        short8 a2 = *(const short8*)(hb + lr * 256 + ((ks * 64 + lg * 16) ^ ((lr & 7) << 4)));
        short8 bz = *(const short8*)&w2p[lr * 128 + ks * 32 + lg * 8];
        acc2 = MFMA_BF16(a2, bz, acc2, 0, 0, 0);
    }
    if (lr < 2) {
#pragma unroll
        for (int r = 0; r < 4; ++r) {
            int gpo = gp0 + lg * 4 + r;
            float v = acc2[r];
            if (lr == 0) {
                out[gpo * 2] = v;
            } else {
                float sp = (v > 20.f) ? v : log1pf(expf(v));
                out[gpo * 2 + 1] = sp + 0.01f;
            }
        }
    }
}

// ---------------------------------------------------------------------------
extern "C" void kernel_launch(void* const* d_in, const int* in_sizes, int n_in,
                              void* d_out, int out_size, void* d_ws, size_t ws_size,
                              hipStream_t stream) {
    const float* h_grid = (const float*)d_in[0];
    const float* xs = (const float*)d_in[1];
    const float* ys = (const float*)d_in[2];
    const float* Bm = (const float*)d_in[3];
    const float* W0 = (const float*)d_in[4];
    const float* b0 = (const float*)d_in[5];
    const float* W1 = (const float*)d_in[6];
    const float* b1 = (const float*)d_in[7];
    const float* W2 = (const float*)d_in[8];
    const float* b2 = (const float*)d_in[9];
    float* out = (float*)d_out;

    // ws carve: ht (134217728 B) | w0t (98304 B) | w1t (32768 B) | w2p (4096 B)
    unsigned short* ht  = (unsigned short*)d_ws;
    unsigned short* w0t = (unsigned short*)((char*)d_ws + 134217728ull);
    unsigned short* w1t = w0t + 128 * 384;
    unsigned short* w2p = w1t + 128 * 128;

    hipLaunchKernelGGL(transpose_h, dim3(16384), dim3(256), 0, stream, h_grid, ht);
    hipLaunchKernelGGL(prep_weights, dim3(64), dim3(256), 0, stream, W0, W1, W2, w0t, w1t, w2p);
    hipLaunchKernelGGL(fused_decoder, dim3(1024), dim3(1024), 0, stream,
                       ht, xs, ys, Bm, w0t, b0, w1t, b1, w2p, b2, out);
}